// Round 9
// baseline (593.319 us; speedup 1.0000x reference)
//
#include <hip/hip_runtime.h>
#include <hip/hip_bf16.h>
#include <math.h>

#define NTOK 16384
#define DM 1024
#define DFF 4096
#define NEXP 8
#define CAP 2560

typedef __bf16 bf16;
typedef float f32x4 __attribute__((ext_vector_type(4)));
typedef bf16 bf16x8 __attribute__((ext_vector_type(8)));
typedef bf16 bf16x4 __attribute__((ext_vector_type(4)));

// ---------------- workspace layout (bytes) ----------------
#define OFF_PROBS 0ull                 // E*N f32          = 524288
#define OFF_IDX   524288ull            // E*CAP i32        = 81920
#define OFF_WTS   606208ull            // E*CAP f32        = 81920
#define OFF_W1T   688128ull            // E*F*D bf16       = 67108864
#define OFF_W2T   67796992ull          // E*D*F bf16       = 67108864
#define OFF_X     134905856ull         // E*CAP*D bf16     = 41943040
#define OFF_ENT   OFF_X                // 4096 f32 (overlay: dead before gather writes X)
#define OFF_H     176848896ull         // fused: E*CAP*F bf16 = 167772160
#define WS_MIN    197820416ull
#define WS_FUSED  344621056ull

__device__ __forceinline__ void gl16(const bf16* g, const bf16* l) {
  __builtin_amdgcn_global_load_lds((const __attribute__((address_space(1))) void*)g,
                                   (__attribute__((address_space(3))) void*)l, 16, 0, 0);
}

// inline-asm ds_read_b128: invisible to the compiler's LDS-DMA alias tracking, so it
// cannot re-insert a vmcnt(0) drain before fragment reads while staging loads are in
// flight. Ordering enforced by explicit counted vmcnt/lgkmcnt + sched_barrier (rule #18).
__device__ __forceinline__ bf16x8 ldsrd16(const bf16* a) {
  bf16x8 d;
  asm volatile("ds_read_b128 %0, %1"
               : "=v"(d)
               : "v"((const __attribute__((address_space(3))) bf16*)a));
  return d;
}

#define LGKM(N) do { asm volatile("s_waitcnt lgkmcnt(%0)" :: "n"(N)); \
                     __builtin_amdgcn_sched_barrier(0); } while (0)

__device__ __forceinline__ float gelu_f(float x) {
  // tanh-approx GELU via sigmoid; |err vs erf-gelu| < 4e-4 (validated r1-r8, absmax 2e-3)
  float u = 1.5957691216057308f * (x + 0.044715f * x * x * x);
  return x * __builtin_amdgcn_rcpf(1.f + __expf(-u));
}

// ---------------- transpose + convert fp32 -> bf16 ----------------
__global__ __launch_bounds__(256) void k_transpose_cvt(const float* __restrict__ src,
                                                       bf16* __restrict__ dst, int R, int C) {
  __shared__ float tile[64][69];
  int e = blockIdx.z;
  src += (size_t)e * R * C;
  dst += (size_t)e * R * C;
  int c0 = blockIdx.x * 64, r0 = blockIdx.y * 64;
  int t = threadIdx.x;
  int tr = t >> 4, tc4 = (t & 15) * 4;
#pragma unroll
  for (int i = 0; i < 4; i++) {
    int r = tr + i * 16;
    float4 v = *(const float4*)(src + (size_t)(r0 + r) * C + c0 + tc4);
    tile[r][tc4] = v.x; tile[r][tc4 + 1] = v.y; tile[r][tc4 + 2] = v.z; tile[r][tc4 + 3] = v.w;
  }
  __syncthreads();
#pragma unroll
  for (int i = 0; i < 4; i++) {
    int orr = tr + i * 16;
    bf16x4 o = {(bf16)tile[tc4][orr], (bf16)tile[tc4 + 1][orr],
                (bf16)tile[tc4 + 2][orr], (bf16)tile[tc4 + 3][orr]};
    *(bf16x4*)(dst + (size_t)(c0 + orr) * R + r0 + tc4) = o;
  }
}

// ---------------- router (fp-order stable since r1: selection set must be exact) --------
__global__ __launch_bounds__(256) void k_router(const float* __restrict__ hidden,
                                                const float* __restrict__ rw,
                                                float* __restrict__ probsT,
                                                float* __restrict__ entPart) {
  __shared__ float went[4];
  int wv = threadIdx.x >> 6, lane = threadIdx.x & 63;
  int token = blockIdx.x * 4 + wv;
  float acc[NEXP];
#pragma unroll
  for (int e = 0; e < NEXP; e++) acc[e] = 0.f;
  const float* hp = hidden + (size_t)token * DM;
  for (int d = lane; d < DM; d += 64) {
    float h = hp[d];
#pragma unroll
    for (int e = 0; e < NEXP; e++) acc[e] = fmaf(h, rw[d * NEXP + e], acc[e]);
  }
#pragma unroll
  for (int e = 0; e < NEXP; e++) {
    float v = acc[e];
#pragma unroll
    for (int s = 1; s < 64; s <<= 1) v += __shfl_xor(v, s);
    acc[e] = v;
  }
  float mx = acc[0];
#pragma unroll
  for (int e = 1; e < NEXP; e++) mx = fmaxf(mx, acc[e]);
  float p[NEXP], s = 0.f;
#pragma unroll
  for (int e = 0; e < NEXP; e++) { p[e] = expf(acc[e] - mx); s += p[e]; }
  float inv = 1.f / s;
  float ent = 0.f;
#pragma unroll
  for (int e = 0; e < NEXP; e++) { p[e] *= inv; ent += p[e] * logf(p[e] + 1e-8f); }
  if (lane < NEXP) probsT[(size_t)lane * NTOK + token] = p[lane];
  if (lane == 0) went[wv] = ent;
  __syncthreads();
  if (threadIdx.x == 0) entPart[blockIdx.x] = went[0] + went[1] + went[2] + went[3];
}

__global__ __launch_bounds__(256) void k_aux(const float* __restrict__ part, float* __restrict__ outAux) {
  __shared__ float s[256];
  int t = threadIdx.x;
  float v = 0.f;
#pragma unroll
  for (int i = 0; i < 16; i++) v += part[i * 256 + t];
  s[t] = v;
  __syncthreads();
  for (int st = 128; st > 0; st >>= 1) {
    if (t < st) s[t] += s[t + st];
    __syncthreads();
  }
  if (t == 0) outAux[0] = s[0] * (1.f / (float)NTOK);
}

// ---------------- exact top-k per expert ----------------
__global__ __launch_bounds__(1024) void k_topk(const float* __restrict__ probsT,
                                               int* __restrict__ idx,
                                               float* __restrict__ wts) {
  int e = blockIdx.x;
  const float* row = probsT + (size_t)e * NTOK;
  int t = threadIdx.x;
  unsigned u[16];
#pragma unroll
  for (int j = 0; j < 16; j++) u[j] = __float_as_uint(row[j * 1024 + t]);
  __shared__ int wred[16];
  __shared__ int bc;
  __shared__ int cnt_gt, cnt_eq;
  __shared__ int eqbuf[2048];
  int lane = t & 63, wv = t >> 6;
  unsigned prefix = 0;
  for (int bit = 30; bit >= 0; bit--) {
    unsigned cand = prefix | (1u << bit);
    int c = 0;
#pragma unroll
    for (int j = 0; j < 16; j++) c += (u[j] >= cand) ? 1 : 0;
#pragma unroll
    for (int s = 1; s < 64; s <<= 1) c += __shfl_xor(c, s);
    if (lane == 0) wred[wv] = c;
    __syncthreads();
    if (t == 0) { int tot = 0; for (int k = 0; k < 16; k++) tot += wred[k]; bc = tot; }
    __syncthreads();
    if (bc >= CAP) prefix = cand;
  }
  unsigned vC = prefix;
  if (t == 0) { cnt_gt = 0; cnt_eq = 0; }
  __syncthreads();
#pragma unroll
  for (int j = 0; j < 16; j++) {
    int i = j * 1024 + t;
    if (u[j] > vC) {
      int p = atomicAdd(&cnt_gt, 1);
      idx[e * CAP + p] = i;
      wts[e * CAP + p] = __uint_as_float(u[j]);
    } else if (u[j] == vC) {
      int p = atomicAdd(&cnt_eq, 1);
      if (p < 2048) eqbuf[p] = i;
    }
  }
  __syncthreads();
  int m = cnt_gt;
  int ne = cnt_eq > 2048 ? 2048 : cnt_eq;
  int needed = CAP - m;
  for (int j = t; j < ne; j += 1024) {
    int my = eqbuf[j];
    int rank = 0;
    for (int k = 0; k < ne; k++) rank += (eqbuf[k] < my) ? 1 : 0;
    if (rank < needed) {
      idx[e * CAP + m + rank] = my;
      wts[e * CAP + m + rank] = __uint_as_float(vC);
    }
  }
}

// ---------------- gather selected tokens -> bf16 ----------------
__global__ void k_gather(const float* __restrict__ hidden, const int* __restrict__ idx,
                         bf16* __restrict__ X) {
  int ec = blockIdx.x;
  int token = idx[ec];
  const float4* src = (const float4*)(hidden + (size_t)token * DM);
  bf16* dstrow = X + (size_t)ec * DM;
  int t = threadIdx.x;
  float4 v = src[t];
  bf16x4 o = {(bf16)v.x, (bf16)v.y, (bf16)v.z, (bf16)v.w};
  *(bf16x4*)(dstrow + t * 4) = o;
}

// ---------------- 2-phase dbuf MFMA GEMM with intra-tile LDS||MFMA interleave ----------
// r8 shapes/grids/staging unchanged; ONLY the inner tile is restructured: counted
// lgkmcnt interleave so fragment reads of chunk q+1 are in flight during MFMAs of
// chunk q (the per-CU LDS pipe ~2304cy and MFMA pipe ~2483cy overlap instead of
// running serially). FIFO accounting per wait is in comments; DS completes in order.
template <int EPI, int BM, int BN, int WMW, int WNW, int NT, int KD>
__global__ __launch_bounds__(512) void k_gemm2ph(
    const bf16* __restrict__ Ab, const bf16* __restrict__ Bb,
    bf16* __restrict__ Hb, const int* __restrict__ idxb, const float* __restrict__ wtsb,
    float* __restrict__ outb, int serialE) {
  constexpr int MF = (BM / WMW) / 16;     // m-frags per wave (8 for GEMM1, 4 for GEMM2)
  constexpr int NF = (BN / WNW) / 16;     // n-frags per wave (4)
  constexpr int CA = BM / 8;              // A chunks (1KB each)
  constexpr int CB = BN / 8;              // B chunks
  constexpr int S = (CA + CB) / 8;        // gl16 per thread per tile

  __shared__ bf16 As[2][BM * 64];
  __shared__ bf16 Bs[2][BN * 64];

  int e, j;
  if (serialE >= 0) { e = serialE; j = blockIdx.x; }
  else { e = blockIdx.x & 7; j = blockIdx.x >> 3; }
  int m0 = (j % 10) * 256;
  int n0 = (j / 10) * BN;

  const bf16* A = Ab + (size_t)e * CAP * KD + (size_t)m0 * KD;
  const bf16* B = Bb + (size_t)e * DFF * DM + (size_t)n0 * KD;

  int t = threadIdx.x, lane = t & 63, wv = t >> 6;
  int wm = wv / WNW, wn = wv % WNW;
  int l3 = lane >> 3, l7 = lane & 7, l15 = lane & 15, khalf = lane >> 4;
  int cswz = (l7 ^ l3) * 8;  // pre-swizzled global col offset (elems)

  const bf16* gA0 = A + (size_t)l3 * KD + cswz;
  const bf16* gB0 = B + (size_t)l3 * KD + cswz;

  f32x4 acc[MF][NF];
#pragma unroll
  for (int m = 0; m < MF; m++)
#pragma unroll
    for (int n = 0; n < NF; n++) acc[m][n] = (f32x4){0.f, 0.f, 0.f, 0.f};

  auto STAGE = [&](int buf, int ke) {
#pragma unroll
    for (int s = 0; s < S; s++) {
      int c = wv + s * 8;
      if (c < CA) gl16(gA0 + (size_t)(c * 8) * KD + ke, &As[buf][c * 512 + lane * 8]);
      else gl16(gB0 + (size_t)((c - CA) * 8) * KD + ke, &Bs[buf][(c - CA) * 512 + lane * 8]);
    }
  };

  STAGE(0, 0);  // prologue: S loads in flight

  int rowA = wm * (BM / WMW) + l15;
  int rowB = wn * (BN / WNW) + l15;

  for (int kt = 0; kt < NT; kt++) {
    int cur = kt & 1;
    if (kt < NT - 1) {
      STAGE(cur ^ 1, (kt + 1) * 64);                 // outstanding <= 2S
      asm volatile("s_waitcnt vmcnt(%0)" :: "n"(S)); // tile kt landed (oldest S)
    } else {
      asm volatile("s_waitcnt vmcnt(0)");
    }
    __builtin_amdgcn_s_barrier();                    // all waves: buf[cur] ready

    const char* Ap = (const char*)&As[cur][0];
    const char* Bp = (const char*)&Bs[cur][0];
    int slt0 = ((0 + khalf) ^ l7) * 16;
    int slt1 = ((4 + khalf) ^ l7) * 16;
    bf16x8 aF[MF][2], bF[NF][2];

    // issue: B kk0 (NF), A kk0 (MF), B kk1 (NF)  -> outstanding = MF+2NF
#pragma unroll
    for (int n = 0; n < NF; n++) bF[n][0] = ldsrd16((const bf16*)(Bp + (rowB + n * 16) * 128 + slt0));
#pragma unroll
    for (int m = 0; m < MF; m++) aF[m][0] = ldsrd16((const bf16*)(Ap + (rowA + m * 16) * 128 + slt0));
#pragma unroll
    for (int n = 0; n < NF; n++) bF[n][1] = ldsrd16((const bf16*)(Bp + (rowB + n * 16) * 128 + slt1));
    LGKM(NF);  // kk0 frags (oldest NF+MF) landed; <=NF (Bkk1) outstanding

    if constexpr (MF == 8) {
      // MFMA kk0 m0-3  || issue A kk1 m0-3 between the halves
#pragma unroll
      for (int m = 0; m < 4; m++)
#pragma unroll
        for (int n = 0; n < NF; n++)
          acc[m][n] = __builtin_amdgcn_mfma_f32_16x16x32_bf16(aF[m][0], bF[n][0], acc[m][n], 0, 0, 0);
#pragma unroll
      for (int m = 0; m < 4; m++) aF[m][1] = ldsrd16((const bf16*)(Ap + (rowA + m * 16) * 128 + slt1));
#pragma unroll
      for (int m = 4; m < 8; m++)
#pragma unroll
        for (int n = 0; n < NF; n++)
          acc[m][n] = __builtin_amdgcn_mfma_f32_16x16x32_bf16(aF[m][0], bF[n][0], acc[m][n], 0, 0, 0);
#pragma unroll
      for (int m = 4; m < 8; m++) aF[m][1] = ldsrd16((const bf16*)(Ap + (rowA + m * 16) * 128 + slt1));
      // outstanding <= Bkk1(4)+Akk1(8)=12 ; wait oldest 8 (Bkk1 + Akk1 m0-3) -> remain 4
      LGKM(4);
#pragma unroll
      for (int m = 0; m < 4; m++)
#pragma unroll
        for (int n = 0; n < NF; n++)
          acc[m][n] = __builtin_amdgcn_mfma_f32_16x16x32_bf16(aF[m][1], bF[n][1], acc[m][n], 0, 0, 0);
      LGKM(0);
      __builtin_amdgcn_s_barrier();                  // all reads done: buf may be restaged
#pragma unroll
      for (int m = 4; m < 8; m++)
#pragma unroll
        for (int n = 0; n < NF; n++)
          acc[m][n] = __builtin_amdgcn_mfma_f32_16x16x32_bf16(aF[m][1], bF[n][1], acc[m][n], 0, 0, 0);
    } else {
      // MF == 4: MFMA kk0 m0-1 || A kk1 reads || MFMA kk0 m2-3
#pragma unroll
      for (int m = 0; m < 2; m++)
#pragma unroll
        for (int n = 0; n < NF; n++)
          acc[m][n] = __builtin_amdgcn_mfma_f32_16x16x32_bf16(aF[m][0], bF[n][0], acc[m][n], 0, 0, 0);
#pragma unroll
      for (int m = 0; m < 4; m++) aF[m][1] = ldsrd16((const bf16*)(Ap + (rowA + m * 16) * 128 + slt1));
#pragma unroll
      for (int m = 2; m < 4; m++)
#pragma unroll
        for (int n = 0; n < NF; n++)
          acc[m][n] = __builtin_amdgcn_mfma_f32_16x16x32_bf16(aF[m][0], bF[n][0], acc[m][n], 0, 0, 0);
      // outstanding <= Bkk1(4)+Akk1(4)=8 ; wait oldest 6 (Bkk1 + Akk1 m0-1) -> remain 2
      LGKM(2);
#pragma unroll
      for (int m = 0; m < 2; m++)
#pragma unroll
        for (int n = 0; n < NF; n++)
          acc[m][n] = __builtin_amdgcn_mfma_f32_16x16x32_bf16(aF[m][1], bF[n][1], acc[m][n], 0, 0, 0);
      LGKM(0);
      __builtin_amdgcn_s_barrier();                  // all reads done: buf may be restaged
#pragma unroll
      for (int m = 2; m < 4; m++)
#pragma unroll
        for (int n = 0; n < NF; n++)
          acc[m][n] = __builtin_amdgcn_mfma_f32_16x16x32_bf16(aF[m][1], bF[n][1], acc[m][n], 0, 0, 0);
    }
  }

  int cl = lane & 15, rg = (lane >> 4) * 4;
  if constexpr (EPI == 0) {
    bf16* He = Hb + (size_t)e * CAP * DFF;
#pragma unroll
    for (int m = 0; m < MF; m++) {
      int rowg = m0 + wm * (BM / WMW) + m * 16 + rg;
#pragma unroll
      for (int n = 0; n < NF; n++) {
        int col = n0 + wn * (BN / WNW) + n * 16 + cl;
#pragma unroll
        for (int rr = 0; rr < 4; rr++)
          He[(size_t)(rowg + rr) * DFF + col] = (bf16)gelu_f(acc[m][n][rr]);
      }
    }
  } else {
    const int* idxE = idxb + e * CAP;
    const float* wtsE = wtsb + e * CAP;
#pragma unroll
    for (int m = 0; m < MF; m++) {
      int rowg = m0 + wm * (BM / WMW) + m * 16 + rg;
#pragma unroll
      for (int rr = 0; rr < 4; rr++) {
        int c = rowg + rr;
        int token = idxE[c];
        float w = wtsE[c];
        float* op = outb + (size_t)token * DM + n0 + wn * (BN / WNW) + cl;
#pragma unroll
        for (int n = 0; n < NF; n++) atomicAdd(op + n * 16, w * acc[m][n][rr]);
      }
    }
  }
}

extern "C" void kernel_launch(void* const* d_in, const int* in_sizes, int n_in,
                              void* d_out, int out_size, void* d_ws, size_t ws_size,
                              hipStream_t stream) {
  const float* hidden = (const float*)d_in[0];
  const float* router_w = (const float*)d_in[1];
  const float* W1 = (const float*)d_in[2];
  const float* W2 = (const float*)d_in[3];
  float* out = (float*)d_out;
  if (ws_size < WS_MIN) return;

  char* ws = (char*)d_ws;
  float* probsT = (float*)(ws + OFF_PROBS);
  int* idxb = (int*)(ws + OFF_IDX);
  float* wtsb = (float*)(ws + OFF_WTS);
  bf16* W1T = (bf16*)(ws + OFF_W1T);
  bf16* W2T = (bf16*)(ws + OFF_W2T);
  bf16* Xall = (bf16*)(ws + OFF_X);
  float* entPart = (float*)(ws + OFF_ENT);
  bf16* Hbuf = (bf16*)(ws + OFF_H);

  hipMemsetAsync(d_out, 0, (size_t)out_size * sizeof(float), stream);

  k_transpose_cvt<<<dim3(DFF / 64, DM / 64, NEXP), 256, 0, stream>>>(W1, W1T, DM, DFF);
  k_transpose_cvt<<<dim3(DM / 64, DFF / 64, NEXP), 256, 0, stream>>>(W2, W2T, DFF, DM);

  k_router<<<NTOK / 4, 256, 0, stream>>>(hidden, router_w, probsT, entPart);
  k_aux<<<1, 256, 0, stream>>>(entPart, out + (size_t)NTOK * DM);
  k_topk<<<NEXP, 1024, 0, stream>>>(probsT, idxb, wtsb);
  k_gather<<<NEXP * CAP, 256, 0, stream>>>(hidden, idxb, Xall);

  if (ws_size >= WS_FUSED) {
    k_gemm2ph<0, 256, 256, 2, 4, 16, DM><<<NEXP * 160, 512, 0, stream>>>(
        Xall, W1T, Hbuf, nullptr, nullptr, nullptr, -1);
    k_gemm2ph<1, 256, 128, 4, 2, 64, DFF><<<NEXP * 80, 512, 0, stream>>>(
        Hbuf, W2T, nullptr, idxb, wtsb, out, -1);
  } else {
    for (int e = 0; e < NEXP; e++) {
      bf16* Hadj = Hbuf - (size_t)e * CAP * DFF;  // cancels the e-offset inside the kernel
      k_gemm2ph<0, 256, 256, 2, 4, 16, DM><<<160, 512, 0, stream>>>(
          Xall, W1T, Hadj, nullptr, nullptr, nullptr, e);
      k_gemm2ph<1, 256, 128, 4, 2, 64, DFF><<<80, 512, 0, stream>>>(
          Hadj, W2T, nullptr, idxb, wtsb, out, e);
    }
  }
}

// Round 10
// 541.091 us; speedup vs baseline: 1.0965x; 1.0965x over previous
//
#include <hip/hip_runtime.h>
#include <hip/hip_bf16.h>
#include <math.h>

#define NTOK 16384
#define DM 1024
#define DFF 4096
#define NEXP 8
#define CAP 2560

typedef __bf16 bf16;
typedef float f32x4 __attribute__((ext_vector_type(4)));
typedef bf16 bf16x8 __attribute__((ext_vector_type(8)));
typedef bf16 bf16x4 __attribute__((ext_vector_type(4)));

// ---------------- workspace layout (bytes) ----------------
#define OFF_PROBS 0ull                 // E*N f32          = 524288
#define OFF_IDX   524288ull            // E*CAP i32        = 81920
#define OFF_WTS   606208ull            // E*CAP f32        = 81920
#define OFF_W1T   688128ull            // E*F*D bf16       = 67108864
#define OFF_W2T   67796992ull          // E*D*F bf16       = 67108864
#define OFF_X     134905856ull         // E*CAP*D bf16     = 41943040
#define OFF_ENT   OFF_X                // 4096 f32 (overlay: dead before gather writes X)
#define OFF_H     176848896ull         // fused: E*CAP*F bf16 = 167772160
#define WS_MIN    197820416ull
#define WS_FUSED  344621056ull

__device__ __forceinline__ void gl16(const bf16* g, const bf16* l) {
  __builtin_amdgcn_global_load_lds((const __attribute__((address_space(1))) void*)g,
                                   (__attribute__((address_space(3))) void*)l, 16, 0, 0);
}

// inline-asm ds_read_b128: invisible to the compiler's LDS-DMA alias tracking, so it
// cannot re-insert a vmcnt(0) drain before fragment reads while staging loads are in
// flight. Ordering enforced by explicit counted vmcnt/lgkmcnt + sched_barrier (rule #18).
__device__ __forceinline__ bf16x8 ldsrd16(const bf16* a) {
  bf16x8 d;
  asm volatile("ds_read_b128 %0, %1"
               : "=v"(d)
               : "v"((const __attribute__((address_space(3))) bf16*)a));
  return d;
}

#define LGKM(N) do { asm volatile("s_waitcnt lgkmcnt(%0)" :: "n"(N)); \
                     __builtin_amdgcn_sched_barrier(0); } while (0)

__device__ __forceinline__ float gelu_f(float x) {
  // tanh-approx GELU via sigmoid; |err vs erf-gelu| < 4e-4 (validated r1-r9, absmax 2e-3)
  float u = 1.5957691216057308f * (x + 0.044715f * x * x * x);
  return x * __builtin_amdgcn_rcpf(1.f + __expf(-u));
}

// ---------------- transpose + convert fp32 -> bf16 ----------------
__global__ __launch_bounds__(256) void k_transpose_cvt(const float* __restrict__ src,
                                                       bf16* __restrict__ dst, int R, int C) {
  __shared__ float tile[64][69];
  int e = blockIdx.z;
  src += (size_t)e * R * C;
  dst += (size_t)e * R * C;
  int c0 = blockIdx.x * 64, r0 = blockIdx.y * 64;
  int t = threadIdx.x;
  int tr = t >> 4, tc4 = (t & 15) * 4;
#pragma unroll
  for (int i = 0; i < 4; i++) {
    int r = tr + i * 16;
    float4 v = *(const float4*)(src + (size_t)(r0 + r) * C + c0 + tc4);
    tile[r][tc4] = v.x; tile[r][tc4 + 1] = v.y; tile[r][tc4 + 2] = v.z; tile[r][tc4 + 3] = v.w;
  }
  __syncthreads();
#pragma unroll
  for (int i = 0; i < 4; i++) {
    int orr = tr + i * 16;
    bf16x4 o = {(bf16)tile[tc4][orr], (bf16)tile[tc4 + 1][orr],
                (bf16)tile[tc4 + 2][orr], (bf16)tile[tc4 + 3][orr]};
    *(bf16x4*)(dst + (size_t)(c0 + orr) * R + r0 + tc4) = o;
  }
}

// ---------------- router (fp-order stable since r1: selection set must be exact) --------
__global__ __launch_bounds__(256) void k_router(const float* __restrict__ hidden,
                                                const float* __restrict__ rw,
                                                float* __restrict__ probsT,
                                                float* __restrict__ entPart) {
  __shared__ float went[4];
  int wv = threadIdx.x >> 6, lane = threadIdx.x & 63;
  int token = blockIdx.x * 4 + wv;
  float acc[NEXP];
#pragma unroll
  for (int e = 0; e < NEXP; e++) acc[e] = 0.f;
  const float* hp = hidden + (size_t)token * DM;
  for (int d = lane; d < DM; d += 64) {
    float h = hp[d];
#pragma unroll
    for (int e = 0; e < NEXP; e++) acc[e] = fmaf(h, rw[d * NEXP + e], acc[e]);
  }
#pragma unroll
  for (int e = 0; e < NEXP; e++) {
    float v = acc[e];
#pragma unroll
    for (int s = 1; s < 64; s <<= 1) v += __shfl_xor(v, s);
    acc[e] = v;
  }
  float mx = acc[0];
#pragma unroll
  for (int e = 1; e < NEXP; e++) mx = fmaxf(mx, acc[e]);
  float p[NEXP], s = 0.f;
#pragma unroll
  for (int e = 0; e < NEXP; e++) { p[e] = expf(acc[e] - mx); s += p[e]; }
  float inv = 1.f / s;
  float ent = 0.f;
#pragma unroll
  for (int e = 0; e < NEXP; e++) { p[e] *= inv; ent += p[e] * logf(p[e] + 1e-8f); }
  if (lane < NEXP) probsT[(size_t)lane * NTOK + token] = p[lane];
  if (lane == 0) went[wv] = ent;
  __syncthreads();
  if (threadIdx.x == 0) entPart[blockIdx.x] = went[0] + went[1] + went[2] + went[3];
}

__global__ __launch_bounds__(256) void k_aux(const float* __restrict__ part, float* __restrict__ outAux) {
  __shared__ float s[256];
  int t = threadIdx.x;
  float v = 0.f;
#pragma unroll
  for (int i = 0; i < 16; i++) v += part[i * 256 + t];
  s[t] = v;
  __syncthreads();
  for (int st = 128; st > 0; st >>= 1) {
    if (t < st) s[t] += s[t + st];
    __syncthreads();
  }
  if (t == 0) outAux[0] = s[0] * (1.f / (float)NTOK);
}

// ---------------- exact top-k per expert ----------------
__global__ __launch_bounds__(1024) void k_topk(const float* __restrict__ probsT,
                                               int* __restrict__ idx,
                                               float* __restrict__ wts) {
  int e = blockIdx.x;
  const float* row = probsT + (size_t)e * NTOK;
  int t = threadIdx.x;
  unsigned u[16];
#pragma unroll
  for (int j = 0; j < 16; j++) u[j] = __float_as_uint(row[j * 1024 + t]);
  __shared__ int wred[16];
  __shared__ int bc;
  __shared__ int cnt_gt, cnt_eq;
  __shared__ int eqbuf[2048];
  int lane = t & 63, wv = t >> 6;
  unsigned prefix = 0;
  for (int bit = 30; bit >= 0; bit--) {
    unsigned cand = prefix | (1u << bit);
    int c = 0;
#pragma unroll
    for (int j = 0; j < 16; j++) c += (u[j] >= cand) ? 1 : 0;
#pragma unroll
    for (int s = 1; s < 64; s <<= 1) c += __shfl_xor(c, s);
    if (lane == 0) wred[wv] = c;
    __syncthreads();
    if (t == 0) { int tot = 0; for (int k = 0; k < 16; k++) tot += wred[k]; bc = tot; }
    __syncthreads();
    if (bc >= CAP) prefix = cand;
  }
  unsigned vC = prefix;
  if (t == 0) { cnt_gt = 0; cnt_eq = 0; }
  __syncthreads();
#pragma unroll
  for (int j = 0; j < 16; j++) {
    int i = j * 1024 + t;
    if (u[j] > vC) {
      int p = atomicAdd(&cnt_gt, 1);
      idx[e * CAP + p] = i;
      wts[e * CAP + p] = __uint_as_float(u[j]);
    } else if (u[j] == vC) {
      int p = atomicAdd(&cnt_eq, 1);
      if (p < 2048) eqbuf[p] = i;
    }
  }
  __syncthreads();
  int m = cnt_gt;
  int ne = cnt_eq > 2048 ? 2048 : cnt_eq;
  int needed = CAP - m;
  for (int j = t; j < ne; j += 1024) {
    int my = eqbuf[j];
    int rank = 0;
    for (int k = 0; k < ne; k++) rank += (eqbuf[k] < my) ? 1 : 0;
    if (rank < needed) {
      idx[e * CAP + m + rank] = my;
      wts[e * CAP + m + rank] = __uint_as_float(vC);
    }
  }
}

// ---------------- gather selected tokens -> bf16 ----------------
__global__ void k_gather(const float* __restrict__ hidden, const int* __restrict__ idx,
                         bf16* __restrict__ X) {
  int ec = blockIdx.x;
  int token = idx[ec];
  const float4* src = (const float4*)(hidden + (size_t)token * DM);
  bf16* dstrow = X + (size_t)ec * DM;
  int t = threadIdx.x;
  float4 v = src[t];
  bf16x4 o = {(bf16)v.x, (bf16)v.y, (bf16)v.z, (bf16)v.w};
  *(bf16x4*)(dstrow + t * 4) = o;
}

// ---------------- 2-phase dbuf MFMA GEMM (counted vmcnt, asm ds_read, XOR swizzle) ------
// EPI0 (GEMM1, unchanged r8 control): BM=256,BN=256, 2x4 waves (wave 128x64), KD=DM,
//   NT=16, gelu->H. grid e x (10 x 16) = 1280 -> 5 exact rounds.
// EPI1 (GEMM2, r10 test): BM=320,BN=256, 2x4 waves (wave 160x64, MF=10), KD=DFF, NT=64,
//   atomic scatter. grid e x (8 x 4) = 256 -> EXACTLY 1 round (was 640 blocks / 3 rounds
//   at 83% utilization). LDS (320+256)*64*2*2 = 144 KiB. Full K: no split, atomics minimal.
template <int EPI, int BM, int BN, int WMW, int WNW, int NT, int KD>
__global__ __launch_bounds__(512) void k_gemm2ph(
    const bf16* __restrict__ Ab, const bf16* __restrict__ Bb,
    bf16* __restrict__ Hb, const int* __restrict__ idxb, const float* __restrict__ wtsb,
    float* __restrict__ outb, int serialE) {
  constexpr int MF = (BM / WMW) / 16;     // m-frags per wave
  constexpr int NF = (BN / WNW) / 16;     // n-frags per wave
  constexpr int CA = BM / 8;              // A chunks (1KB each)
  constexpr int CB = BN / 8;              // B chunks
  constexpr int S = (CA + CB) / 8;        // gl16 per thread per tile
  constexpr int MT = CAP / BM;            // m-tiles

  __shared__ bf16 As[2][BM * 64];
  __shared__ bf16 Bs[2][BN * 64];

  int e, j;
  if (serialE >= 0) { e = serialE; j = blockIdx.x; }
  else { e = blockIdx.x & 7; j = blockIdx.x >> 3; }
  int m0 = (j % MT) * BM;
  int n0 = (j / MT) * BN;

  const bf16* A = Ab + (size_t)e * CAP * KD + (size_t)m0 * KD;
  const bf16* B = Bb + (size_t)e * DFF * DM + (size_t)n0 * KD;

  int t = threadIdx.x, lane = t & 63, wv = t >> 6;
  int wm = wv / WNW, wn = wv % WNW;
  int l3 = lane >> 3, l7 = lane & 7, l15 = lane & 15, khalf = lane >> 4;
  int cswz = (l7 ^ l3) * 8;  // pre-swizzled global col offset (elems)

  const bf16* gA0 = A + (size_t)l3 * KD + cswz;
  const bf16* gB0 = B + (size_t)l3 * KD + cswz;

  f32x4 acc[MF][NF];
#pragma unroll
  for (int m = 0; m < MF; m++)
#pragma unroll
    for (int n = 0; n < NF; n++) acc[m][n] = (f32x4){0.f, 0.f, 0.f, 0.f};

  auto STAGE = [&](int buf, int ke) {
#pragma unroll
    for (int s = 0; s < S; s++) {
      int c = wv + s * 8;
      if (c < CA) gl16(gA0 + (size_t)(c * 8) * KD + ke, &As[buf][c * 512 + lane * 8]);
      else gl16(gB0 + (size_t)((c - CA) * 8) * KD + ke, &Bs[buf][(c - CA) * 512 + lane * 8]);
    }
  };

  STAGE(0, 0);  // prologue: S loads in flight

  int rowA = wm * (BM / WMW) + l15;
  int rowB = wn * (BN / WNW) + l15;

  for (int kt = 0; kt < NT; kt++) {
    int cur = kt & 1;
    if (kt < NT - 1) {
      STAGE(cur ^ 1, (kt + 1) * 64);                 // outstanding <= 2S
      asm volatile("s_waitcnt vmcnt(%0)" :: "n"(S)); // tile kt landed (oldest S)
    } else {
      asm volatile("s_waitcnt vmcnt(0)");
    }
    __builtin_amdgcn_s_barrier();                    // all waves: buf[cur] ready

    const char* Ap = (const char*)&As[cur][0];
    const char* Bp = (const char*)&Bs[cur][0];
    int slt0 = ((0 + khalf) ^ l7) * 16;
    int slt1 = ((4 + khalf) ^ l7) * 16;

    // ---- kk0: read all frags, drain, MFMA ----
    {
      bf16x8 aF[MF], bF[NF];
#pragma unroll
      for (int m = 0; m < MF; m++) aF[m] = ldsrd16((const bf16*)(Ap + (rowA + m * 16) * 128 + slt0));
#pragma unroll
      for (int n = 0; n < NF; n++) bF[n] = ldsrd16((const bf16*)(Bp + (rowB + n * 16) * 128 + slt0));
      LGKM(0);
#pragma unroll
      for (int m = 0; m < MF; m++)
#pragma unroll
        for (int n = 0; n < NF; n++)
          acc[m][n] = __builtin_amdgcn_mfma_f32_16x16x32_bf16(aF[m], bF[n], acc[m][n], 0, 0, 0);
    }
    // ---- kk1: read all frags, drain, release buf, MFMA ----
    {
      bf16x8 aF[MF], bF[NF];
#pragma unroll
      for (int m = 0; m < MF; m++) aF[m] = ldsrd16((const bf16*)(Ap + (rowA + m * 16) * 128 + slt1));
#pragma unroll
      for (int n = 0; n < NF; n++) bF[n] = ldsrd16((const bf16*)(Bp + (rowB + n * 16) * 128 + slt1));
      LGKM(0);
      __builtin_amdgcn_s_barrier();                  // all reads done: buf may be restaged
#pragma unroll
      for (int m = 0; m < MF; m++)
#pragma unroll
        for (int n = 0; n < NF; n++)
          acc[m][n] = __builtin_amdgcn_mfma_f32_16x16x32_bf16(aF[m], bF[n], acc[m][n], 0, 0, 0);
    }
  }

  int cl = lane & 15, rg = (lane >> 4) * 4;
  if constexpr (EPI == 0) {
    bf16* He = Hb + (size_t)e * CAP * DFF;
#pragma unroll
    for (int m = 0; m < MF; m++) {
      int rowg = m0 + wm * (BM / WMW) + m * 16 + rg;
#pragma unroll
      for (int n = 0; n < NF; n++) {
        int col = n0 + wn * (BN / WNW) + n * 16 + cl;
#pragma unroll
        for (int rr = 0; rr < 4; rr++)
          He[(size_t)(rowg + rr) * DFF + col] = (bf16)gelu_f(acc[m][n][rr]);
      }
    }
  } else {
    const int* idxE = idxb + e * CAP;
    const float* wtsE = wtsb + e * CAP;
#pragma unroll
    for (int m = 0; m < MF; m++) {
      int rowg = m0 + wm * (BM / WMW) + m * 16 + rg;
#pragma unroll
      for (int rr = 0; rr < 4; rr++) {
        int c = rowg + rr;
        int token = idxE[c];
        float w = wtsE[c];
        float* op = outb + (size_t)token * DM + n0 + wn * (BN / WNW) + cl;
#pragma unroll
        for (int n = 0; n < NF; n++) atomicAdd(op + n * 16, w * acc[m][n][rr]);
      }
    }
  }
}

extern "C" void kernel_launch(void* const* d_in, const int* in_sizes, int n_in,
                              void* d_out, int out_size, void* d_ws, size_t ws_size,
                              hipStream_t stream) {
  const float* hidden = (const float*)d_in[0];
  const float* router_w = (const float*)d_in[1];
  const float* W1 = (const float*)d_in[2];
  const float* W2 = (const float*)d_in[3];
  float* out = (float*)d_out;
  if (ws_size < WS_MIN) return;

  char* ws = (char*)d_ws;
  float* probsT = (float*)(ws + OFF_PROBS);
  int* idxb = (int*)(ws + OFF_IDX);
  float* wtsb = (float*)(ws + OFF_WTS);
  bf16* W1T = (bf16*)(ws + OFF_W1T);
  bf16* W2T = (bf16*)(ws + OFF_W2T);
  bf16* Xall = (bf16*)(ws + OFF_X);
  float* entPart = (float*)(ws + OFF_ENT);
  bf16* Hbuf = (bf16*)(ws + OFF_H);

  hipMemsetAsync(d_out, 0, (size_t)out_size * sizeof(float), stream);

  k_transpose_cvt<<<dim3(DFF / 64, DM / 64, NEXP), 256, 0, stream>>>(W1, W1T, DM, DFF);
  k_transpose_cvt<<<dim3(DM / 64, DFF / 64, NEXP), 256, 0, stream>>>(W2, W2T, DFF, DM);

  k_router<<<NTOK / 4, 256, 0, stream>>>(hidden, router_w, probsT, entPart);
  k_aux<<<1, 256, 0, stream>>>(entPart, out + (size_t)NTOK * DM);
  k_topk<<<NEXP, 1024, 0, stream>>>(probsT, idxb, wtsb);
  k_gather<<<NEXP * CAP, 256, 0, stream>>>(hidden, idxb, Xall);

  if (ws_size >= WS_FUSED) {
    k_gemm2ph<0, 256, 256, 2, 4, 16, DM><<<NEXP * 160, 512, 0, stream>>>(
        Xall, W1T, Hbuf, nullptr, nullptr, nullptr, -1);
    k_gemm2ph<1, 320, 256, 2, 4, 64, DFF><<<NEXP * 32, 512, 0, stream>>>(
        Hbuf, W2T, nullptr, idxb, wtsb, out, -1);
  } else {
    for (int e = 0; e < NEXP; e++) {
      bf16* Hadj = Hbuf - (size_t)e * CAP * DFF;  // cancels the e-offset inside the kernel
      k_gemm2ph<0, 256, 256, 2, 4, 16, DM><<<160, 512, 0, stream>>>(
          Xall, W1T, Hadj, nullptr, nullptr, nullptr, e);
      k_gemm2ph<1, 320, 256, 2, 4, 64, DFF><<<32, 512, 0, stream>>>(
          Hadj, W2T, nullptr, idxb, wtsb, out, e);
    }
  }
}